// Round 1
// baseline (582.802 us; speedup 1.0000x reference)
//
#include <hip/hip_runtime.h>
#include <hip/hip_bf16.h>
#include <cstdint>

// Problem constants
static constexpr int Bc  = 4;
static constexpr int Sc  = 8192;
static constexpr int Dc  = 1024;
static constexpr int Hc  = 16;
static constexpr int HDc = 64;
static constexpr int ADc = 64;
static constexpr int BHc = Bc * Hc;   // 64
static constexpr int Mc  = Bc * Sc;   // 32768
static constexpr int N3c = 3 * Dc;    // 3072
static constexpr float EPSc = 1e-6f;

using bf16x8 = __attribute__((ext_vector_type(8))) __bf16;
using f32x4  = __attribute__((ext_vector_type(4))) float;

__device__ __forceinline__ ushort f2bf(float f) {
  union { float f; uint32_t u; } v; v.f = f;
  uint32_t u = v.u;
  return (ushort)((u + 0x7fffu + ((u >> 16) & 1u)) >> 16);  // RNE
}
__device__ __forceinline__ float bf2f(ushort h) {
  union { uint32_t u; float f; } v; v.u = ((uint32_t)h) << 16;
  return v.f;
}

// ---------------------------------------------------------------- kernel 0: fp32 -> bf16 convert
__global__ __launch_bounds__(256) void cvt_bf16_k(const float* __restrict__ src,
                                                  ushort* __restrict__ dst, int n4) {
  int i = blockIdx.x * 256 + threadIdx.x;
  if (i < n4) {
    float4 v = reinterpret_cast<const float4*>(src)[i];
    ushort4 o; o.x = f2bf(v.x); o.y = f2bf(v.y); o.z = f2bf(v.z); o.w = f2bf(v.w);
    reinterpret_cast<ushort4*>(dst)[i] = o;
  }
}

// ---------------------------------------------------------------- kernel 1: QKV GEMM
// C[m, n] = dot(x[m, :], W_qkv[n, :]) + b[n];  writes Q/K/V in [B,H,S,64] bf16 layout.
__global__ __launch_bounds__(256) void qkv_gemm_k(const float* __restrict__ x,
                                                  const ushort* __restrict__ W3b,
                                                  const float* __restrict__ bqkv,
                                                  ushort* __restrict__ Qb,
                                                  ushort* __restrict__ Kb,
                                                  ushort* __restrict__ Vb) {
  __shared__ ushort As[128][72];  // +8 pad keeps 16B align, breaks pow2 stride
  __shared__ ushort Bs[128][72];
  const int t  = threadIdx.x;
  const int n0 = blockIdx.x * 128;
  const int m0 = blockIdx.y * 128;
  const int wave = t >> 6, lane = t & 63;
  const int wm = wave >> 1, wn = wave & 1;
  const int lr = lane & 15;       // A-row / B-col / D-col within fragment
  const int kg = lane >> 4;       // k group

  f32x4 acc[4][4];
#pragma unroll
  for (int i = 0; i < 4; i++)
#pragma unroll
    for (int j = 0; j < 4; j++) acc[i][j] = (f32x4){0.f, 0.f, 0.f, 0.f};

  for (int kt = 0; kt < 1024; kt += 64) {
    __syncthreads();
    // stage A: 128 rows x 64 k of x, fp32 -> bf16
#pragma unroll
    for (int i = 0; i < 8; i++) {
      int li = i * 256 + t;            // 0..2047 (float4 units)
      int r = li >> 4, c4 = li & 15;
      float4 v = *reinterpret_cast<const float4*>(&x[(size_t)(m0 + r) * 1024 + kt + c4 * 4]);
      ushort4 o; o.x = f2bf(v.x); o.y = f2bf(v.y); o.z = f2bf(v.z); o.w = f2bf(v.w);
      *reinterpret_cast<ushort4*>(&As[r][c4 * 4]) = o;
    }
    // stage B: 128 rows x 64 k of W3b (bf16, row-major = B^T form)
#pragma unroll
    for (int i = 0; i < 4; i++) {
      int li = i * 256 + t;            // 0..1023 (ushort8 units)
      int r = li >> 3, c8 = li & 7;
      *reinterpret_cast<uint4*>(&Bs[r][c8 * 8]) =
          *reinterpret_cast<const uint4*>(&W3b[(size_t)(n0 + r) * 1024 + kt + c8 * 8]);
    }
    __syncthreads();
#pragma unroll
    for (int ks = 0; ks < 64; ks += 32) {
      bf16x8 af[4], bfr[4];
#pragma unroll
      for (int i = 0; i < 4; i++)
        af[i] = *reinterpret_cast<const bf16x8*>(&As[wm * 64 + i * 16 + lr][ks + kg * 8]);
#pragma unroll
      for (int j = 0; j < 4; j++)
        bfr[j] = *reinterpret_cast<const bf16x8*>(&Bs[wn * 64 + j * 16 + lr][ks + kg * 8]);
#pragma unroll
      for (int i = 0; i < 4; i++)
#pragma unroll
        for (int j = 0; j < 4; j++)
          acc[i][j] = __builtin_amdgcn_mfma_f32_16x16x32_bf16(af[i], bfr[j], acc[i][j], 0, 0, 0);
    }
  }

  // epilogue: scatter into head layout. wave's 64 cols lie inside one head of one part.
  const int n0w  = n0 + wn * 64;
  const int part = n0w >> 10;          // 0=Q 1=K 2=V
  const int h    = (n0w & 1023) >> 6;  // head
  ushort* dst = (part == 0) ? Qb : (part == 1 ? Kb : Vb);
  const int bq     = m0 >> 13;         // m0 / 8192
  const int s_base = (m0 & 8191) + wm * 64;
  const size_t hb  = ((size_t)(bq * Hc + h)) * Sc * 64;
#pragma unroll
  for (int j = 0; j < 4; j++) {
    int col = j * 16 + lr;             // hd within head
    float bias = bqkv[n0w + col];
#pragma unroll
    for (int i = 0; i < 4; i++) {
#pragma unroll
      for (int r = 0; r < 4; r++) {
        int s = s_base + i * 16 + kg * 4 + r;
        dst[hb + (size_t)s * 64 + col] = f2bf(acc[i][j][r] + bias);
      }
    }
  }
}

// ---------------------------------------------------------------- kernel 2: phi = sqrt(1+(Q W_p^T + b)^2), in place
__global__ __launch_bounds__(256) void phi_k(ushort* __restrict__ Qb, ushort* __restrict__ Kb,
                                             const ushort* __restrict__ Wpb,
                                             const float* __restrict__ bp) {
  __shared__ ushort Qs[256][72];
  __shared__ ushort Ws[64][72];
  const int t  = threadIdx.x;
  const int bh = blockIdx.y;
  const int s0 = blockIdx.x * 256;
  ushort* base = (blockIdx.z == 0 ? Qb : Kb) + (size_t)bh * Sc * 64 + (size_t)s0 * 64;

#pragma unroll
  for (int i = 0; i < 8; i++) {      // 2048 x ushort8 = 256 rows x 64
    int li = i * 256 + t;
    int r = li >> 3, c8 = li & 7;
    *reinterpret_cast<uint4*>(&Qs[r][c8 * 8]) = *reinterpret_cast<const uint4*>(&base[li * 8]);
  }
#pragma unroll
  for (int i = 0; i < 2; i++) {      // 512 x ushort8 = 64 x 64
    int li = i * 256 + t;
    int r = li >> 3, c8 = li & 7;
    *reinterpret_cast<uint4*>(&Ws[r][c8 * 8]) = *reinterpret_cast<const uint4*>(&Wpb[li * 8]);
  }
  __syncthreads();

  const int wave = t >> 6, lane = t & 63, lr = lane & 15, kg = lane >> 4;
  f32x4 acc[4][4];
#pragma unroll
  for (int i = 0; i < 4; i++)
#pragma unroll
    for (int j = 0; j < 4; j++) acc[i][j] = (f32x4){0.f, 0.f, 0.f, 0.f};

#pragma unroll
  for (int ks = 0; ks < 64; ks += 32) {
    bf16x8 af[4], bfr[4];
#pragma unroll
    for (int i = 0; i < 4; i++)
      af[i] = *reinterpret_cast<const bf16x8*>(&Qs[wave * 64 + i * 16 + lr][ks + kg * 8]);
#pragma unroll
    for (int j = 0; j < 4; j++)
      bfr[j] = *reinterpret_cast<const bf16x8*>(&Ws[j * 16 + lr][ks + kg * 8]);
#pragma unroll
    for (int i = 0; i < 4; i++)
#pragma unroll
      for (int j = 0; j < 4; j++)
        acc[i][j] = __builtin_amdgcn_mfma_f32_16x16x32_bf16(af[i], bfr[j], acc[i][j], 0, 0, 0);
  }

#pragma unroll
  for (int j = 0; j < 4; j++) {
    int col = j * 16 + lr;
    float bias = bp[col];
#pragma unroll
    for (int i = 0; i < 4; i++) {
#pragma unroll
      for (int r = 0; r < 4; r++) {
        int row = wave * 64 + i * 16 + kg * 4 + r;
        float p = acc[i][j][r] + bias;
        base[(size_t)row * 64 + col] = f2bf(sqrtf(1.f + p * p));
      }
    }
  }
}

// ---------------------------------------------------------------- kernel 3: per-chunk KTV partials + ksum partials
// KTV[bh][a][v] = sum_s phiK[bh][s][a] * V[bh][s][v];  chunk = 512 rows of s.
__global__ __launch_bounds__(256) void ktv_part_k(const ushort* __restrict__ Kphi,
                                                  const ushort* __restrict__ Vb,
                                                  float* __restrict__ KTVp,
                                                  float* __restrict__ ksump) {
  __shared__ ushort KsT[64][136];   // [a][s]  (transposed)
  __shared__ ushort VsT[64][136];   // [v][s]
  __shared__ float  red[64][65];
  const int t = threadIdx.x;
  const int chunk = blockIdx.x, bh = blockIdx.y;
  const int wave = t >> 6, lane = t & 63, lr = lane & 15, kg = lane >> 4;
  const size_t hb = (size_t)bh * Sc * 64;

  f32x4 acc[4][4];
#pragma unroll
  for (int i = 0; i < 4; i++)
#pragma unroll
    for (int j = 0; j < 4; j++) acc[i][j] = (f32x4){0.f, 0.f, 0.f, 0.f};
  float ks_acc = 0.f;

  for (int sub = 0; sub < 4; sub++) {
    const int sb = chunk * 512 + sub * 128;
    __syncthreads();
    // transpose-stage 128 rows of phiK and V (ushort4 loads, scalar scatter writes)
#pragma unroll
    for (int i = 0; i < 8; i++) {
      int li = i * 256 + t;              // 0..2047 (ushort4 units)
      int s = li >> 4, a4 = (li & 15) * 4;
      ushort4 kv = *reinterpret_cast<const ushort4*>(&Kphi[hb + (size_t)(sb + s) * 64 + a4]);
      ushort4 vv = *reinterpret_cast<const ushort4*>(&Vb[hb + (size_t)(sb + s) * 64 + a4]);
      KsT[a4 + 0][s] = kv.x; KsT[a4 + 1][s] = kv.y; KsT[a4 + 2][s] = kv.z; KsT[a4 + 3][s] = kv.w;
      VsT[a4 + 0][s] = vv.x; VsT[a4 + 1][s] = vv.y; VsT[a4 + 2][s] = vv.z; VsT[a4 + 3][s] = vv.w;
    }
    __syncthreads();
    {
      const int ko = wave * 32 + kg * 8;   // waves split the 128-deep K range
      bf16x8 af[4], bfr[4];
#pragma unroll
      for (int i = 0; i < 4; i++)
        af[i] = *reinterpret_cast<const bf16x8*>(&KsT[i * 16 + lr][ko]);
#pragma unroll
      for (int j = 0; j < 4; j++)
        bfr[j] = *reinterpret_cast<const bf16x8*>(&VsT[j * 16 + lr][ko]);
#pragma unroll
      for (int i = 0; i < 4; i++)
#pragma unroll
        for (int j = 0; j < 4; j++)
          acc[i][j] = __builtin_amdgcn_mfma_f32_16x16x32_bf16(af[i], bfr[j], acc[i][j], 0, 0, 0);
    }
    if (t < 64) {
      float s = 0.f;
      for (int ss = 0; ss < 128; ss++) s += bf2f(KsT[t][ss]);
      ks_acc += s;
    }
  }

  // deterministic cross-wave reduce through LDS
  __syncthreads();
  for (int li = t; li < 64 * 65; li += 256) (&red[0][0])[li] = 0.f;
  __syncthreads();
  for (int w = 0; w < 4; w++) {
    if (wave == w) {
#pragma unroll
      for (int i = 0; i < 4; i++)
#pragma unroll
        for (int j = 0; j < 4; j++)
#pragma unroll
          for (int r = 0; r < 4; r++)
            red[i * 16 + kg * 4 + r][j * 16 + lr] += acc[i][j][r];
    }
    __syncthreads();
  }
  float* outp = KTVp + ((size_t)bh * 16 + chunk) * 4096;
  for (int li = t; li < 4096; li += 256) outp[li] = red[li >> 6][li & 63];
  if (t < 64) ksump[((size_t)bh * 16 + chunk) * 64 + t] = ks_acc;
}

// ---------------------------------------------------------------- kernel 3b: reduce partials
__global__ __launch_bounds__(256) void ktv_red_k(const float* __restrict__ KTVp,
                                                 const float* __restrict__ ksump,
                                                 float* __restrict__ KTV,
                                                 float* __restrict__ ksum) {
  const int bh = blockIdx.x, t = threadIdx.x;
  for (int li = t; li < 4096; li += 256) {
    float s = 0.f;
    for (int c = 0; c < 16; c++) s += KTVp[((size_t)bh * 16 + c) * 4096 + li];
    KTV[(size_t)bh * 4096 + li] = s;
  }
  if (t < 64) {
    float s = 0.f;
    for (int c = 0; c < 16; c++) s += ksump[((size_t)bh * 16 + c) * 64 + t];
    ksum[bh * 64 + t] = s;
  }
}

// ---------------------------------------------------------------- kernel 4: numerator + denominator + output
__global__ __launch_bounds__(256) void out_k(const ushort* __restrict__ Qphi,
                                             const float* __restrict__ KTV,
                                             const float* __restrict__ ksum,
                                             float* __restrict__ out) {
  __shared__ ushort Qs[256][72];
  __shared__ ushort BT[64][72];     // KTV^T in bf16: BT[v][a]
  __shared__ float  den[256];
  __shared__ float  kss[64];
  const int t = threadIdx.x;
  const int bh = blockIdx.y, s0 = blockIdx.x * 256;
  const ushort* qb = Qphi + (size_t)bh * Sc * 64 + (size_t)s0 * 64;

#pragma unroll
  for (int i = 0; i < 8; i++) {
    int li = i * 256 + t;
    int r = li >> 3, c8 = li & 7;
    *reinterpret_cast<uint4*>(&Qs[r][c8 * 8]) = *reinterpret_cast<const uint4*>(&qb[li * 8]);
  }
  for (int li = t; li < 4096; li += 256) {
    int a = li >> 6, v = li & 63;
    BT[v][a] = f2bf(KTV[(size_t)bh * 4096 + li]);
  }
  if (t < 64) kss[t] = ksum[bh * 64 + t];
  __syncthreads();

  {  // per-row denominator on VALU
    float d = 0.f;
    for (int a = 0; a < 64; a++) d += bf2f(Qs[t][a]) * kss[a];
    den[t] = d + EPSc;
  }
  __syncthreads();

  const int wave = t >> 6, lane = t & 63, lr = lane & 15, kg = lane >> 4;
  f32x4 acc[4][4];
#pragma unroll
  for (int i = 0; i < 4; i++)
#pragma unroll
    for (int j = 0; j < 4; j++) acc[i][j] = (f32x4){0.f, 0.f, 0.f, 0.f};

#pragma unroll
  for (int ks = 0; ks < 64; ks += 32) {
    bf16x8 af[4], bfr[4];
#pragma unroll
    for (int i = 0; i < 4; i++)
      af[i] = *reinterpret_cast<const bf16x8*>(&Qs[wave * 64 + i * 16 + lr][ks + kg * 8]);
#pragma unroll
    for (int j = 0; j < 4; j++)
      bfr[j] = *reinterpret_cast<const bf16x8*>(&BT[j * 16 + lr][ks + kg * 8]);
#pragma unroll
    for (int i = 0; i < 4; i++)
#pragma unroll
      for (int j = 0; j < 4; j++)
        acc[i][j] = __builtin_amdgcn_mfma_f32_16x16x32_bf16(af[i], bfr[j], acc[i][j], 0, 0, 0);
  }

  const int bq = bh >> 4, h = bh & 15;
#pragma unroll
  for (int i = 0; i < 4; i++) {
#pragma unroll
    for (int j = 0; j < 4; j++) {
#pragma unroll
      for (int r = 0; r < 4; r++) {
        int row = wave * 64 + i * 16 + kg * 4 + r;
        int s = s0 + row;
        int v = j * 16 + lr;
        out[((size_t)bq * Sc + s) * 1024 + h * 64 + v] = acc[i][j][r] / den[row];
      }
    }
  }
}

// ---------------------------------------------------------------- launch
extern "C" void kernel_launch(void* const* d_in, const int* in_sizes, int n_in,
                              void* d_out, int out_size, void* d_ws, size_t ws_size,
                              hipStream_t stream) {
  const float* x     = (const float*)d_in[0];
  const float* W_qkv = (const float*)d_in[1];
  const float* b_qkv = (const float*)d_in[2];
  const float* W_p   = (const float*)d_in[3];
  const float* b_p   = (const float*)d_in[4];
  float* out = (float*)d_out;

  // carve workspace (aligned 256B)
  size_t off = 0;
  auto carve = [&](size_t bytes) -> void* {
    void* p = (char*)d_ws + off;
    off += (bytes + 255) & ~(size_t)255;
    return p;
  };
  const size_t headElems = (size_t)BHc * Sc * 64;           // 33,554,432
  ushort* Qb   = (ushort*)carve(headElems * 2);
  ushort* Kb   = (ushort*)carve(headElems * 2);
  ushort* Vb   = (ushort*)carve(headElems * 2);
  ushort* W3b  = (ushort*)carve((size_t)N3c * Dc * 2);      // 6.3 MB
  ushort* Wpb  = (ushort*)carve((size_t)ADc * HDc * 2);
  float*  KTVp = (float*)carve((size_t)BHc * 16 * 4096 * 4);
  float*  ksmp = (float*)carve((size_t)BHc * 16 * 64 * 4);
  float*  KTV  = (float*)carve((size_t)BHc * 4096 * 4);
  float*  ksum = (float*)carve((size_t)BHc * 64 * 4);
  (void)ws_size; (void)n_in; (void)in_sizes; (void)out_size;

  // 0: convert weights to bf16
  cvt_bf16_k<<<(N3c * Dc / 4 + 255) / 256, 256, 0, stream>>>(W_qkv, W3b, N3c * Dc / 4);
  cvt_bf16_k<<<(ADc * HDc / 4 + 255) / 256, 256, 0, stream>>>(W_p, Wpb, ADc * HDc / 4);
  // 1: QKV GEMM -> head-layout bf16 Q/K/V
  qkv_gemm_k<<<dim3(N3c / 128, Mc / 128), 256, 0, stream>>>(x, W3b, b_qkv, Qb, Kb, Vb);
  // 2: phi in place over Q and K
  phi_k<<<dim3(Sc / 256, BHc, 2), 256, 0, stream>>>(Qb, Kb, Wpb, b_p);
  // 3: KTV + ksum partials, then reduce
  ktv_part_k<<<dim3(16, BHc), 256, 0, stream>>>(Kb, Vb, KTVp, ksmp);
  ktv_red_k<<<BHc, 256, 0, stream>>>(KTVp, ksmp, KTV, ksum);
  // 4: output
  out_k<<<dim3(Sc / 256, BHc), 256, 0, stream>>>(Qb, KTV, ksum, out);
}